// Round 3
// baseline (2197.223 us; speedup 1.0000x reference)
//
#include <hip/hip_runtime.h>
#include <cstdint>

#define B_ 64
#define N_ 4096
#define D_ 256
#define NS_ 8
#define HID_ 512
#define EPS_ 1e-8f
#define SCALE_ 0.0625f
#define LN_EPS_ 1e-5f

// ---------------- transpose GRU weights [768][256] -> [256][768] ----------------
__global__ void k_transpose(const float* __restrict__ wi, const float* __restrict__ wh,
                            float* __restrict__ wiT, float* __restrict__ whT) {
  int idx = blockIdx.x * 256 + threadIdx.x;      // 0..196607
  int o = idx >> 8;                              // 0..767
  int d = idx & 255;
  wiT[d * 768 + o] = wi[idx];
  whT[d * 768 + o] = wh[idx];
}

// ---------------- slots init: mu + exp(logsigma)*noise ----------------
__global__ void k_init_slots(const float* __restrict__ noise, const float* __restrict__ mu,
                             const float* __restrict__ ls, float* __restrict__ slots) {
  int idx = blockIdx.x * 256 + threadIdx.x;      // 0..131071
  int d = idx & 255;
  slots[idx] = mu[d] + __expf(ls[d]) * noise[idx];
}

// ---------------- per-row LN stats of inputs (wave per row) ----------------
__global__ __launch_bounds__(256) void k_stats(const float* __restrict__ in,
                                               float* __restrict__ stats) {
  int wave = threadIdx.x >> 6, lane = threadIdx.x & 63;
  int row = blockIdx.x * 4 + wave;
  const float* r = in + (size_t)row * D_;
  float4 a = *(const float4*)(r + lane * 4);
  float s1 = a.x + a.y + a.z + a.w;
  float s2 = a.x * a.x + a.y * a.y + a.z * a.z + a.w * a.w;
  #pragma unroll
  for (int m = 32; m >= 1; m >>= 1) { s1 += __shfl_xor(s1, m, 64); s2 += __shfl_xor(s2, m, 64); }
  if (lane == 0) {
    float mean = s1 * (1.f / D_);
    float var  = s2 * (1.f / D_) - mean * mean;
    stats[row * 2]     = mean;
    stats[row * 2 + 1] = rsqrtf(var + LN_EPS_);
  }
}

// ---------------- k = LN(x)@Wk, v = LN(x)@Wv   (fp32 tiled GEMM) ----------------
// tile 64 rows x 128 cols, BK=16, thread tile 4x8 (x2 outputs)
__global__ __launch_bounds__(256) void k_kv_gemm(
    const float* __restrict__ in, const float* __restrict__ stats,
    const float* __restrict__ g, const float* __restrict__ bb,
    const float* __restrict__ Wk, const float* __restrict__ Wv,
    float* __restrict__ k, float* __restrict__ v) {
  __shared__ float xT[16][68];
  __shared__ float wks[16][128];
  __shared__ float wvs[16][128];
  const int tid = threadIdx.x;
  const int m0 = blockIdx.x * 64;
  const int c0 = blockIdx.y * 128;
  const int tr = tid >> 4, tc = tid & 15;
  const int sxr = tid >> 2, sxc = (tid & 3) * 4;   // x staging: 4 threads/row
  const float mu = stats[(m0 + sxr) * 2];
  const float rs = stats[(m0 + sxr) * 2 + 1];
  float acck[4][8] = {};
  float accv[4][8] = {};
  for (int dc = 0; dc < 16; ++dc) {
    __syncthreads();
    const int dbase = dc * 16;
    {
      float4 a  = *(const float4*)(in + (size_t)(m0 + sxr) * D_ + dbase + sxc);
      float4 gg = *(const float4*)(g + dbase + sxc);
      float4 bv = *(const float4*)(bb + dbase + sxc);
      xT[sxc + 0][sxr] = (a.x - mu) * rs * gg.x + bv.x;
      xT[sxc + 1][sxr] = (a.y - mu) * rs * gg.y + bv.y;
      xT[sxc + 2][sxr] = (a.z - mu) * rs * gg.z + bv.z;
      xT[sxc + 3][sxr] = (a.w - mu) * rs * gg.w + bv.w;
    }
    {
      int dd = tid >> 4, cc = (tid & 15) * 8;
      const float* wkp = Wk + (size_t)(dbase + dd) * D_ + c0 + cc;
      const float* wvp = Wv + (size_t)(dbase + dd) * D_ + c0 + cc;
      *(float4*)&wks[dd][cc]     = *(const float4*)(wkp);
      *(float4*)&wks[dd][cc + 4] = *(const float4*)(wkp + 4);
      *(float4*)&wvs[dd][cc]     = *(const float4*)(wvp);
      *(float4*)&wvs[dd][cc + 4] = *(const float4*)(wvp + 4);
    }
    __syncthreads();
    #pragma unroll
    for (int dd = 0; dd < 16; ++dd) {
      float4 xa = *(const float4*)&xT[dd][tr * 4];
      float4 k0 = *(const float4*)&wks[dd][tc * 8];
      float4 k1 = *(const float4*)&wks[dd][tc * 8 + 4];
      float4 v0 = *(const float4*)&wvs[dd][tc * 8];
      float4 v1 = *(const float4*)&wvs[dd][tc * 8 + 4];
      float xr[4] = {xa.x, xa.y, xa.z, xa.w};
      float kc[8] = {k0.x, k0.y, k0.z, k0.w, k1.x, k1.y, k1.z, k1.w};
      float vc[8] = {v0.x, v0.y, v0.z, v0.w, v1.x, v1.y, v1.z, v1.w};
      #pragma unroll
      for (int r = 0; r < 4; ++r)
        #pragma unroll
        for (int c = 0; c < 8; ++c) {
          acck[r][c] = fmaf(xr[r], kc[c], acck[r][c]);
          accv[r][c] = fmaf(xr[r], vc[c], accv[r][c]);
        }
    }
  }
  #pragma unroll
  for (int r = 0; r < 4; ++r) {
    size_t off = (size_t)(m0 + tr * 4 + r) * D_ + c0 + tc * 8;
    *(float4*)&k[off]     = make_float4(acck[r][0], acck[r][1], acck[r][2], acck[r][3]);
    *(float4*)&k[off + 4] = make_float4(acck[r][4], acck[r][5], acck[r][6], acck[r][7]);
    *(float4*)&v[off]     = make_float4(accv[r][0], accv[r][1], accv[r][2], accv[r][3]);
    *(float4*)&v[off + 4] = make_float4(accv[r][4], accv[r][5], accv[r][6], accv[r][7]);
  }
}

// ---------------- q = LN(slots)@Wq * SCALE  (block per row) ----------------
__global__ __launch_bounds__(256) void k_qproj(const float* __restrict__ slots,
    const float* __restrict__ g, const float* __restrict__ b,
    const float* __restrict__ Wq, float* __restrict__ q) {
  const int row = blockIdx.x;
  const int t = threadIdx.x;
  __shared__ float sl[256];
  __shared__ float red1[4], red2[4];
  float val = slots[(size_t)row * D_ + t];
  float s1 = val, s2 = val * val;
  #pragma unroll
  for (int m = 32; m >= 1; m >>= 1) { s1 += __shfl_xor(s1, m, 64); s2 += __shfl_xor(s2, m, 64); }
  int wave = t >> 6, lane = t & 63;
  if (lane == 0) { red1[wave] = s1; red2[wave] = s2; }
  __syncthreads();
  s1 = red1[0] + red1[1] + red1[2] + red1[3];
  s2 = red2[0] + red2[1] + red2[2] + red2[3];
  float mean = s1 * (1.f / D_);
  float var  = s2 * (1.f / D_) - mean * mean;
  float rstd = rsqrtf(var + LN_EPS_);
  sl[t] = (val - mean) * rstd * g[t] + b[t];
  __syncthreads();
  float acc = 0.f;
  #pragma unroll 4
  for (int d = 0; d < D_; ++d) acc = fmaf(sl[d], Wq[d * D_ + t], acc);
  q[(size_t)row * D_ + t] = acc * SCALE_;
}

// ---------------- dots + softmax(slots) + EPS -> w, and asum atomics ----------------
// block: 128 threads, 256 tokens (2/thread), batch = blockIdx.y
__global__ __launch_bounds__(128) void k_attn(const float* __restrict__ k,
    const float* __restrict__ q, float* __restrict__ w, float* __restrict__ asum) {
  const int b = blockIdx.y;
  const int jt = blockIdx.x * 256;
  const int tid = threadIdx.x;
  __shared__ float lk[256 * 18];
  const float* kb = k + ((size_t)b * N_ + jt) * D_;
  const float* qb = q + (size_t)b * NS_ * D_;
  float dots[2][8];
  #pragma unroll
  for (int t = 0; t < 2; ++t)
    #pragma unroll
    for (int i = 0; i < 8; ++i) dots[t][i] = 0.f;
  for (int dc = 0; dc < 16; ++dc) {
    __syncthreads();
    const int r0 = tid >> 2, c4 = (tid & 3) * 4;
    #pragma unroll
    for (int rp = 0; rp < 8; ++rp) {
      int row = r0 + rp * 32;
      float4 a = *(const float4*)(kb + (size_t)row * D_ + dc * 16 + c4);
      float* dst = &lk[row * 18 + c4];
      dst[0] = a.x; dst[1] = a.y; dst[2] = a.z; dst[3] = a.w;
    }
    __syncthreads();
    #pragma unroll
    for (int d2 = 0; d2 < 16; d2 += 2) {
      float2 ka = *(const float2*)&lk[tid * 18 + d2];
      float2 kc = *(const float2*)&lk[(tid + 128) * 18 + d2];
      #pragma unroll
      for (int i = 0; i < 8; ++i) {
        float q0 = qb[i * D_ + dc * 16 + d2];
        float q1 = qb[i * D_ + dc * 16 + d2 + 1];
        dots[0][i] = fmaf(ka.x, q0, fmaf(ka.y, q1, dots[0][i]));
        dots[1][i] = fmaf(kc.x, q0, fmaf(kc.y, q1, dots[1][i]));
      }
    }
  }
  float lsum[8] = {0.f, 0.f, 0.f, 0.f, 0.f, 0.f, 0.f, 0.f};
  float* wb = w + ((size_t)b * N_ + jt) * NS_;
  #pragma unroll
  for (int t = 0; t < 2; ++t) {
    int j = tid + t * 128;
    float m = dots[t][0];
    #pragma unroll
    for (int i = 1; i < 8; ++i) m = fmaxf(m, dots[t][i]);
    float e[8]; float s = 0.f;
    #pragma unroll
    for (int i = 0; i < 8; ++i) { e[i] = __expf(dots[t][i] - m); s += e[i]; }
    float is = 1.f / s;
    float wv[8];
    #pragma unroll
    for (int i = 0; i < 8; ++i) { wv[i] = e[i] * is + EPS_; lsum[i] += wv[i]; }
    float4* dst = (float4*)(wb + (size_t)j * NS_);
    dst[0] = make_float4(wv[0], wv[1], wv[2], wv[3]);
    dst[1] = make_float4(wv[4], wv[5], wv[6], wv[7]);
  }
  #pragma unroll
  for (int i = 0; i < 8; ++i) {
    float vv = lsum[i];
    #pragma unroll
    for (int m = 32; m >= 1; m >>= 1) vv += __shfl_xor(vv, m, 64);
    if ((tid & 63) == 0) atomicAdd(&asum[b * NS_ + i], vv);
  }
}

// ---------------- updates_unnorm[b,i,d] += sum_j w[b,j,i]*v[b,j,d] ----------------
// block: 256 threads, 512-token chunk; wave owns 2 slots, lane owns 4 d
__global__ __launch_bounds__(256) void k_updates(const float* __restrict__ v,
    const float* __restrict__ w, float* __restrict__ upd) {
  const int b = blockIdx.y;
  const int j0 = blockIdx.x * 512;
  const int tid = threadIdx.x;
  const int wave = tid >> 6, lane = tid & 63;
  const int i0 = wave * 2;
  const float* vb = v + ((size_t)b * N_ + j0) * D_;
  const float* wb = w + ((size_t)b * N_ + j0) * NS_;
  float a0[4] = {0.f, 0.f, 0.f, 0.f};
  float a1[4] = {0.f, 0.f, 0.f, 0.f};
  #pragma unroll 4
  for (int jj = 0; jj < 512; ++jj) {
    float4 vv = *(const float4*)(vb + (size_t)jj * D_ + lane * 4);
    float wa = wb[jj * NS_ + i0];
    float wc = wb[jj * NS_ + i0 + 1];
    a0[0] = fmaf(wa, vv.x, a0[0]); a0[1] = fmaf(wa, vv.y, a0[1]);
    a0[2] = fmaf(wa, vv.z, a0[2]); a0[3] = fmaf(wa, vv.w, a0[3]);
    a1[0] = fmaf(wc, vv.x, a1[0]); a1[1] = fmaf(wc, vv.y, a1[1]);
    a1[2] = fmaf(wc, vv.z, a1[2]); a1[3] = fmaf(wc, vv.w, a1[3]);
  }
  float* u0 = upd + ((size_t)b * NS_ + i0) * D_ + lane * 4;
  float* u1 = u0 + D_;
  #pragma unroll
  for (int c = 0; c < 4; ++c) { atomicAdd(u0 + c, a0[c]); atomicAdd(u1 + c, a1[c]); }
}

// ---------------- GRU + LN + MLP residual (block per slot-row) ----------------
__global__ __launch_bounds__(256) void k_gru_mlp(
    const float* __restrict__ upd, const float* __restrict__ asum,
    const float* __restrict__ slots,
    const float* __restrict__ wiT, const float* __restrict__ whT,
    const float* __restrict__ bi, const float* __restrict__ bh,
    const float* __restrict__ w1, const float* __restrict__ b1,
    const float* __restrict__ w2, const float* __restrict__ b2,
    const float* __restrict__ gf, const float* __restrict__ bf,
    float* __restrict__ out) {
  const int row = blockIdx.x;   // 0..511 = b*8+i
  const int t = threadIdx.x;
  __shared__ float xs[256], hs[256], ffs[256], hid[512];
  __shared__ float red1[4], red2[4];
  const float ia = 1.f / asum[row];
  const float xv = upd[(size_t)row * D_ + t] * ia;
  const float hv = slots[(size_t)row * D_ + t];
  xs[t] = xv; hs[t] = hv;
  __syncthreads();
  float gi0 = bi[t], gi1 = bi[D_ + t], gi2 = bi[2 * D_ + t];
  float gh0 = bh[t], gh1 = bh[D_ + t], gh2 = bh[2 * D_ + t];
  #pragma unroll 4
  for (int d = 0; d < D_; ++d) {
    float xd = xs[d], hd = hs[d];
    const float* wid = wiT + d * 768;
    const float* whd = whT + d * 768;
    gi0 = fmaf(xd, wid[t], gi0); gi1 = fmaf(xd, wid[D_ + t], gi1); gi2 = fmaf(xd, wid[2 * D_ + t], gi2);
    gh0 = fmaf(hd, whd[t], gh0); gh1 = fmaf(hd, whd[D_ + t], gh1); gh2 = fmaf(hd, whd[2 * D_ + t], gh2);
  }
  float r = 1.f / (1.f + __expf(-(gi0 + gh0)));
  float z = 1.f / (1.f + __expf(-(gi1 + gh1)));
  float n = tanhf(gi2 + r * gh2);
  float hnew = (1.f - z) * n + z * hv;
  // LayerNorm(hnew) across block
  float s1 = hnew, s2 = hnew * hnew;
  #pragma unroll
  for (int m = 32; m >= 1; m >>= 1) { s1 += __shfl_xor(s1, m, 64); s2 += __shfl_xor(s2, m, 64); }
  const int wave = t >> 6, lane = t & 63;
  if (lane == 0) { red1[wave] = s1; red2[wave] = s2; }
  __syncthreads();
  s1 = red1[0] + red1[1] + red1[2] + red1[3];
  s2 = red2[0] + red2[1] + red2[2] + red2[3];
  float mean = s1 * (1.f / D_);
  float var  = s2 * (1.f / D_) - mean * mean;
  float rstd = rsqrtf(var + LN_EPS_);
  ffs[t] = (hnew - mean) * rstd * gf[t] + bf[t];
  __syncthreads();
  float h1 = b1[t], h2 = b1[D_ + t];
  #pragma unroll 4
  for (int d = 0; d < D_; ++d) {
    float f = ffs[d];
    h1 = fmaf(f, w1[(size_t)d * HID_ + t], h1);
    h2 = fmaf(f, w1[(size_t)d * HID_ + D_ + t], h2);
  }
  hid[t] = fmaxf(h1, 0.f); hid[D_ + t] = fmaxf(h2, 0.f);
  __syncthreads();
  float o = b2[t];
  #pragma unroll 4
  for (int d = 0; d < HID_; ++d) o = fmaf(hid[d], w2[(size_t)d * D_ + t], o);
  out[(size_t)row * D_ + t] = o + hnew;
}

extern "C" void kernel_launch(void* const* d_in, const int* in_sizes, int n_in,
                              void* d_out, int out_size, void* d_ws, size_t ws_size,
                              hipStream_t stream) {
  (void)in_sizes; (void)n_in; (void)out_size; (void)ws_size;
  const float* inputs = (const float*)d_in[0];
  const float* noise  = (const float*)d_in[1];
  const float* mu     = (const float*)d_in[2];
  const float* ls     = (const float*)d_in[3];
  const float* Wq     = (const float*)d_in[4];
  const float* Wk     = (const float*)d_in[5];
  const float* Wv     = (const float*)d_in[6];
  const float* gwi    = (const float*)d_in[7];
  const float* gwh    = (const float*)d_in[8];
  const float* gbi    = (const float*)d_in[9];
  const float* gbh    = (const float*)d_in[10];
  const float* w1     = (const float*)d_in[11];
  const float* b1     = (const float*)d_in[12];
  const float* w2     = (const float*)d_in[13];
  const float* b2     = (const float*)d_in[14];
  const float* gin    = (const float*)d_in[15];
  const float* bin    = (const float*)d_in[16];
  const float* gs     = (const float*)d_in[17];
  const float* bs     = (const float*)d_in[18];
  const float* gff    = (const float*)d_in[19];
  const float* bff    = (const float*)d_in[20];

  float* ws    = (float*)d_ws;
  float* k     = ws;
  float* v     = k + (size_t)B_ * N_ * D_;
  float* w     = v + (size_t)B_ * N_ * D_;
  float* stats = w + (size_t)B_ * N_ * NS_;
  float* slots = stats + (size_t)2 * B_ * N_;
  float* q     = slots + B_ * NS_ * D_;
  float* asum  = q + B_ * NS_ * D_;
  float* upd   = asum + 512;
  float* wiT   = upd + B_ * NS_ * D_;
  float* whT   = wiT + 768 * 256;

  k_transpose<<<768, 256, 0, stream>>>(gwi, gwh, wiT, whT);
  k_init_slots<<<512, 256, 0, stream>>>(noise, mu, ls, slots);
  k_stats<<<B_ * N_ / 4, 256, 0, stream>>>(inputs, stats);
  k_kv_gemm<<<dim3(B_ * N_ / 64, 2), 256, 0, stream>>>(inputs, stats, gin, bin, Wk, Wv, k, v);
  for (int it = 0; it < 4; ++it) {
    k_qproj<<<512, 256, 0, stream>>>(slots, gs, bs, Wq, q);
    hipMemsetAsync(asum, 0, (512 + B_ * NS_ * D_) * sizeof(float), stream);
    k_attn<<<dim3(16, 64), 128, 0, stream>>>(k, q, w, asum);
    k_updates<<<dim3(8, 64), 256, 0, stream>>>(v, w, upd);
    float* outp = (it == 3) ? (float*)d_out : slots;
    k_gru_mlp<<<512, 256, 0, stream>>>(upd, asum, slots, wiT, whT, gbi, gbh,
                                       w1, b1, w2, b2, gff, bff, outp);
  }
}

// Round 4
// 1342.268 us; speedup vs baseline: 1.6369x; 1.6369x over previous
//
#include <hip/hip_runtime.h>
#include <cstdint>

#define B_ 64
#define N_ 4096
#define D_ 256
#define NS_ 8
#define HID_ 512
#define EPS_ 1e-8f
#define SCALE_ 0.0625f
#define LN_EPS_ 1e-5f

typedef _Float16 f16;
typedef __attribute__((ext_vector_type(4))) _Float16 f16x4;
typedef __attribute__((ext_vector_type(8))) _Float16 f16x8;
typedef __attribute__((ext_vector_type(4))) float f32x4;

#define MFMA16(a, b, c) __builtin_amdgcn_mfma_f32_16x16x32_f16(a, b, c, 0, 0, 0)

// ---------------- transpose GRU weights [768][256] -> [256][768] ----------------
__global__ void k_transpose(const float* __restrict__ wi, const float* __restrict__ wh,
                            float* __restrict__ wiT, float* __restrict__ whT) {
  int idx = blockIdx.x * 256 + threadIdx.x;      // 0..196607
  int o = idx >> 8;                              // 0..767
  int d = idx & 255;
  wiT[d * 768 + o] = wi[idx];
  whT[d * 768 + o] = wh[idx];
}

// ---------------- cast+transpose Wk/Wv [d][n] fp32 -> [n][d] fp16 ----------------
__global__ void k_wcast(const float* __restrict__ Wk, const float* __restrict__ Wv,
                        f16* __restrict__ WkT, f16* __restrict__ WvT) {
  int n = blockIdx.x, d = threadIdx.x;
  WkT[n * 256 + d] = (f16)Wk[d * 256 + n];
  WvT[n * 256 + d] = (f16)Wv[d * 256 + n];
}

// ---------------- slots init: mu + exp(logsigma)*noise ----------------
__global__ void k_init_slots(const float* __restrict__ noise, const float* __restrict__ mu,
                             const float* __restrict__ ls, float* __restrict__ slots) {
  int idx = blockIdx.x * 256 + threadIdx.x;      // 0..131071
  int d = idx & 255;
  slots[idx] = mu[d] + __expf(ls[d]) * noise[idx];
}

// ---------------- per-row LN stats of inputs (wave per row) ----------------
__global__ __launch_bounds__(256) void k_stats(const float* __restrict__ in,
                                               float* __restrict__ stats) {
  int wave = threadIdx.x >> 6, lane = threadIdx.x & 63;
  int row = blockIdx.x * 4 + wave;
  const float* r = in + (size_t)row * D_;
  float4 a = *(const float4*)(r + lane * 4);
  float s1 = a.x + a.y + a.z + a.w;
  float s2 = a.x * a.x + a.y * a.y + a.z * a.z + a.w * a.w;
  #pragma unroll
  for (int m = 32; m >= 1; m >>= 1) { s1 += __shfl_xor(s1, m, 64); s2 += __shfl_xor(s2, m, 64); }
  if (lane == 0) {
    float mean = s1 * (1.f / D_);
    float var  = s2 * (1.f / D_) - mean * mean;
    stats[row * 2]     = mean;
    stats[row * 2 + 1] = rsqrtf(var + LN_EPS_);
  }
}

// ---------------- k = LN(x)@Wk, v = LN(x)@Wv  (fp16 MFMA, fp32 accum) ----------------
// block: 512 thr (8 waves), tile 128 rows x 256 cols (full width), BK=32, outputs both k,v fp16
__global__ __launch_bounds__(512) void k_kv_mfma(
    const float* __restrict__ in, const float* __restrict__ stats,
    const float* __restrict__ g, const float* __restrict__ bb,
    const f16* __restrict__ WkT, const f16* __restrict__ WvT,
    f16* __restrict__ k, f16* __restrict__ v) {
  __shared__ f16 As[128 * 32];    // [row][d]  8 KB
  __shared__ f16 Bks[256 * 32];   // [n][d]   16 KB
  __shared__ f16 Bvs[256 * 32];   // [n][d]   16 KB
  const int tid = threadIdx.x;
  const int m0 = blockIdx.x * 128;
  // A staging: thread -> (row, 8 d's); fixed across K steps
  const int arow = tid >> 2;
  const int acol = (tid & 3) * 8;
  const float mu = stats[(m0 + arow) * 2];
  const float rs = stats[(m0 + arow) * 2 + 1];
  // B staging: thread -> (n, 16 d's)
  const int bn = tid >> 1;
  const int bd = (tid & 1) * 16;
  // wave -> output subtile
  const int wid = tid >> 6;
  const int lane = tid & 63;
  const int wr = wid >> 1;            // 0..3: rows wr*32..+32
  const int wc = wid & 1;             // 0..1: cols wc*128..+128
  const int frow = lane & 15;
  const int kgrp = (lane >> 4) * 8;

  f32x4 acck[2][8], accv[2][8];
  #pragma unroll
  for (int f = 0; f < 2; ++f)
    #pragma unroll
    for (int c = 0; c < 8; ++c) {
      acck[f][c] = (f32x4){0.f, 0.f, 0.f, 0.f};
      accv[f][c] = (f32x4){0.f, 0.f, 0.f, 0.f};
    }

  #pragma unroll 1
  for (int kk = 0; kk < 8; ++kk) {
    const int d0 = kk * 32;
    __syncthreads();
    // stage A (LN applied, fp32 -> fp16)
    {
      const float* src = in + (size_t)(m0 + arow) * D_ + d0 + acol;
      float4 x0 = *(const float4*)(src);
      float4 x1 = *(const float4*)(src + 4);
      float4 g0 = *(const float4*)(g + d0 + acol);
      float4 g1 = *(const float4*)(g + d0 + acol + 4);
      float4 b0 = *(const float4*)(bb + d0 + acol);
      float4 b1 = *(const float4*)(bb + d0 + acol + 4);
      f16x8 av;
      av[0] = (f16)((x0.x - mu) * rs * g0.x + b0.x);
      av[1] = (f16)((x0.y - mu) * rs * g0.y + b0.y);
      av[2] = (f16)((x0.z - mu) * rs * g0.z + b0.z);
      av[3] = (f16)((x0.w - mu) * rs * g0.w + b0.w);
      av[4] = (f16)((x1.x - mu) * rs * g1.x + b1.x);
      av[5] = (f16)((x1.y - mu) * rs * g1.y + b1.y);
      av[6] = (f16)((x1.z - mu) * rs * g1.z + b1.z);
      av[7] = (f16)((x1.w - mu) * rs * g1.w + b1.w);
      *(f16x8*)&As[arow * 32 + acol] = av;
    }
    // stage B (already fp16, [n][d] layout)
    {
      const f16* sk = WkT + (size_t)bn * 256 + d0 + bd;
      const f16* sv = WvT + (size_t)bn * 256 + d0 + bd;
      *(f16x8*)&Bks[bn * 32 + bd]     = *(const f16x8*)(sk);
      *(f16x8*)&Bks[bn * 32 + bd + 8] = *(const f16x8*)(sk + 8);
      *(f16x8*)&Bvs[bn * 32 + bd]     = *(const f16x8*)(sv);
      *(f16x8*)&Bvs[bn * 32 + bd + 8] = *(const f16x8*)(sv + 8);
    }
    __syncthreads();
    f16x8 af[2];
    #pragma unroll
    for (int f = 0; f < 2; ++f)
      af[f] = *(const f16x8*)&As[(wr * 32 + f * 16 + frow) * 32 + kgrp];
    #pragma unroll
    for (int cf = 0; cf < 8; ++cf) {
      const int n = wc * 128 + cf * 16 + frow;
      f16x8 bk = *(const f16x8*)&Bks[n * 32 + kgrp];
      f16x8 bv = *(const f16x8*)&Bvs[n * 32 + kgrp];
      acck[0][cf] = MFMA16(af[0], bk, acck[0][cf]);
      acck[1][cf] = MFMA16(af[1], bk, acck[1][cf]);
      accv[0][cf] = MFMA16(af[0], bv, accv[0][cf]);
      accv[1][cf] = MFMA16(af[1], bv, accv[1][cf]);
    }
  }
  // epilogue: D layout col=lane&15, row=(lane>>4)*4+r
  const int drow = (lane >> 4) * 4;
  const int dcol = lane & 15;
  #pragma unroll
  for (int f = 0; f < 2; ++f)
    #pragma unroll
    for (int cf = 0; cf < 8; ++cf) {
      size_t base = (size_t)(m0 + wr * 32 + f * 16 + drow) * D_ + wc * 128 + cf * 16 + dcol;
      #pragma unroll
      for (int r = 0; r < 4; ++r) {
        k[base + (size_t)r * D_] = (f16)acck[f][cf][r];
        v[base + (size_t)r * D_] = (f16)accv[f][cf][r];
      }
    }
}

// ---------------- q = LN(slots)@Wq * SCALE  (block per row) ----------------
__global__ __launch_bounds__(256) void k_qproj(const float* __restrict__ slots,
    const float* __restrict__ g, const float* __restrict__ b,
    const float* __restrict__ Wq, float* __restrict__ q) {
  const int row = blockIdx.x;
  const int t = threadIdx.x;
  __shared__ float sl[256];
  __shared__ float red1[4], red2[4];
  float val = slots[(size_t)row * D_ + t];
  float s1 = val, s2 = val * val;
  #pragma unroll
  for (int m = 32; m >= 1; m >>= 1) { s1 += __shfl_xor(s1, m, 64); s2 += __shfl_xor(s2, m, 64); }
  int wave = t >> 6, lane = t & 63;
  if (lane == 0) { red1[wave] = s1; red2[wave] = s2; }
  __syncthreads();
  s1 = red1[0] + red1[1] + red1[2] + red1[3];
  s2 = red2[0] + red2[1] + red2[2] + red2[3];
  float mean = s1 * (1.f / D_);
  float var  = s2 * (1.f / D_) - mean * mean;
  float rstd = rsqrtf(var + LN_EPS_);
  sl[t] = (val - mean) * rstd * g[t] + b[t];
  __syncthreads();
  float acc = 0.f;
  #pragma unroll 4
  for (int d = 0; d < D_; ++d) acc = fmaf(sl[d], Wq[d * D_ + t], acc);
  q[(size_t)row * D_ + t] = acc * SCALE_;
}

// ---------------- dots + softmax(slots) + EPS -> w, and asum atomics ----------------
// block: 128 threads, 256 tokens (2/thread), batch = blockIdx.y; k is fp16
__global__ __launch_bounds__(128) void k_attn(const f16* __restrict__ k,
    const float* __restrict__ q, float* __restrict__ w, float* __restrict__ asum) {
  const int b = blockIdx.y;
  const int jt = blockIdx.x * 256;
  const int tid = threadIdx.x;
  __shared__ float lk[256 * 18];
  const f16* kb = k + ((size_t)b * N_ + jt) * D_;
  const float* qb = q + (size_t)b * NS_ * D_;
  float dots[2][8];
  #pragma unroll
  for (int t = 0; t < 2; ++t)
    #pragma unroll
    for (int i = 0; i < 8; ++i) dots[t][i] = 0.f;
  for (int dc = 0; dc < 16; ++dc) {
    __syncthreads();
    const int r0 = tid >> 2, c4 = (tid & 3) * 4;
    #pragma unroll
    for (int rp = 0; rp < 8; ++rp) {
      int row = r0 + rp * 32;
      f16x4 a = *(const f16x4*)(kb + (size_t)row * D_ + dc * 16 + c4);
      float* dst = &lk[row * 18 + c4];
      dst[0] = (float)a[0]; dst[1] = (float)a[1]; dst[2] = (float)a[2]; dst[3] = (float)a[3];
    }
    __syncthreads();
    #pragma unroll
    for (int d2 = 0; d2 < 16; d2 += 2) {
      float2 ka = *(const float2*)&lk[tid * 18 + d2];
      float2 kc = *(const float2*)&lk[(tid + 128) * 18 + d2];
      #pragma unroll
      for (int i = 0; i < 8; ++i) {
        float q0 = qb[i * D_ + dc * 16 + d2];
        float q1 = qb[i * D_ + dc * 16 + d2 + 1];
        dots[0][i] = fmaf(ka.x, q0, fmaf(ka.y, q1, dots[0][i]));
        dots[1][i] = fmaf(kc.x, q0, fmaf(kc.y, q1, dots[1][i]));
      }
    }
  }
  float lsum[8] = {0.f, 0.f, 0.f, 0.f, 0.f, 0.f, 0.f, 0.f};
  float* wb = w + ((size_t)b * N_ + jt) * NS_;
  #pragma unroll
  for (int t = 0; t < 2; ++t) {
    int j = tid + t * 128;
    float m = dots[t][0];
    #pragma unroll
    for (int i = 1; i < 8; ++i) m = fmaxf(m, dots[t][i]);
    float e[8]; float s = 0.f;
    #pragma unroll
    for (int i = 0; i < 8; ++i) { e[i] = __expf(dots[t][i] - m); s += e[i]; }
    float is = 1.f / s;
    float wv[8];
    #pragma unroll
    for (int i = 0; i < 8; ++i) { wv[i] = e[i] * is + EPS_; lsum[i] += wv[i]; }
    float4* dst = (float4*)(wb + (size_t)j * NS_);
    dst[0] = make_float4(wv[0], wv[1], wv[2], wv[3]);
    dst[1] = make_float4(wv[4], wv[5], wv[6], wv[7]);
  }
  #pragma unroll
  for (int i = 0; i < 8; ++i) {
    float vv = lsum[i];
    #pragma unroll
    for (int m = 32; m >= 1; m >>= 1) vv += __shfl_xor(vv, m, 64);
    if ((tid & 63) == 0) atomicAdd(&asum[b * NS_ + i], vv);
  }
}

// ---------------- updates_unnorm[b,i,d] += sum_j w[b,j,i]*v[b,j,d]  (v fp16) ----------------
__global__ __launch_bounds__(256) void k_updates(const f16* __restrict__ v,
    const float* __restrict__ w, float* __restrict__ upd) {
  const int b = blockIdx.y;
  const int j0 = blockIdx.x * 512;
  const int tid = threadIdx.x;
  const int wave = tid >> 6, lane = tid & 63;
  const int i0 = wave * 2;
  const f16* vb = v + ((size_t)b * N_ + j0) * D_;
  const float* wb = w + ((size_t)b * N_ + j0) * NS_;
  float a0[4] = {0.f, 0.f, 0.f, 0.f};
  float a1[4] = {0.f, 0.f, 0.f, 0.f};
  #pragma unroll 4
  for (int jj = 0; jj < 512; ++jj) {
    f16x4 vv = *(const f16x4*)(vb + (size_t)jj * D_ + lane * 4);
    float vx = (float)vv[0], vy = (float)vv[1], vz = (float)vv[2], vw = (float)vv[3];
    float wa = wb[jj * NS_ + i0];
    float wc = wb[jj * NS_ + i0 + 1];
    a0[0] = fmaf(wa, vx, a0[0]); a0[1] = fmaf(wa, vy, a0[1]);
    a0[2] = fmaf(wa, vz, a0[2]); a0[3] = fmaf(wa, vw, a0[3]);
    a1[0] = fmaf(wc, vx, a1[0]); a1[1] = fmaf(wc, vy, a1[1]);
    a1[2] = fmaf(wc, vz, a1[2]); a1[3] = fmaf(wc, vw, a1[3]);
  }
  float* u0 = upd + ((size_t)b * NS_ + i0) * D_ + lane * 4;
  float* u1 = u0 + D_;
  #pragma unroll
  for (int c = 0; c < 4; ++c) { atomicAdd(u0 + c, a0[c]); atomicAdd(u1 + c, a1[c]); }
}

// ---------------- GRU + LN + MLP residual (block per slot-row) ----------------
__global__ __launch_bounds__(256) void k_gru_mlp(
    const float* __restrict__ upd, const float* __restrict__ asum,
    const float* __restrict__ slots,
    const float* __restrict__ wiT, const float* __restrict__ whT,
    const float* __restrict__ bi, const float* __restrict__ bh,
    const float* __restrict__ w1, const float* __restrict__ b1,
    const float* __restrict__ w2, const float* __restrict__ b2,
    const float* __restrict__ gf, const float* __restrict__ bf,
    float* __restrict__ out) {
  const int row = blockIdx.x;   // 0..511 = b*8+i
  const int t = threadIdx.x;
  __shared__ float xs[256], hs[256], ffs[256], hid[512];
  __shared__ float red1[4], red2[4];
  const float ia = 1.f / asum[row];
  const float xv = upd[(size_t)row * D_ + t] * ia;
  const float hv = slots[(size_t)row * D_ + t];
  xs[t] = xv; hs[t] = hv;
  __syncthreads();
  float gi0 = bi[t], gi1 = bi[D_ + t], gi2 = bi[2 * D_ + t];
  float gh0 = bh[t], gh1 = bh[D_ + t], gh2 = bh[2 * D_ + t];
  #pragma unroll 4
  for (int d = 0; d < D_; ++d) {
    float xd = xs[d], hd = hs[d];
    const float* wid = wiT + d * 768;
    const float* whd = whT + d * 768;
    gi0 = fmaf(xd, wid[t], gi0); gi1 = fmaf(xd, wid[D_ + t], gi1); gi2 = fmaf(xd, wid[2 * D_ + t], gi2);
    gh0 = fmaf(hd, whd[t], gh0); gh1 = fmaf(hd, whd[D_ + t], gh1); gh2 = fmaf(hd, whd[2 * D_ + t], gh2);
  }
  float r = 1.f / (1.f + __expf(-(gi0 + gh0)));
  float z = 1.f / (1.f + __expf(-(gi1 + gh1)));
  float n = tanhf(gi2 + r * gh2);
  float hnew = (1.f - z) * n + z * hv;
  // LayerNorm(hnew) across block
  float s1 = hnew, s2 = hnew * hnew;
  #pragma unroll
  for (int m = 32; m >= 1; m >>= 1) { s1 += __shfl_xor(s1, m, 64); s2 += __shfl_xor(s2, m, 64); }
  const int wave = t >> 6, lane = t & 63;
  if (lane == 0) { red1[wave] = s1; red2[wave] = s2; }
  __syncthreads();
  s1 = red1[0] + red1[1] + red1[2] + red1[3];
  s2 = red2[0] + red2[1] + red2[2] + red2[3];
  float mean = s1 * (1.f / D_);
  float var  = s2 * (1.f / D_) - mean * mean;
  float rstd = rsqrtf(var + LN_EPS_);
  ffs[t] = (hnew - mean) * rstd * gf[t] + bf[t];
  __syncthreads();
  float h1 = b1[t], h2 = b1[D_ + t];
  #pragma unroll 4
  for (int d = 0; d < D_; ++d) {
    float f = ffs[d];
    h1 = fmaf(f, w1[(size_t)d * HID_ + t], h1);
    h2 = fmaf(f, w1[(size_t)d * HID_ + D_ + t], h2);
  }
  hid[t] = fmaxf(h1, 0.f); hid[D_ + t] = fmaxf(h2, 0.f);
  __syncthreads();
  float o = b2[t];
  #pragma unroll 4
  for (int d = 0; d < HID_; ++d) o = fmaf(hid[d], w2[(size_t)d * D_ + t], o);
  out[(size_t)row * D_ + t] = o + hnew;
}

extern "C" void kernel_launch(void* const* d_in, const int* in_sizes, int n_in,
                              void* d_out, int out_size, void* d_ws, size_t ws_size,
                              hipStream_t stream) {
  (void)in_sizes; (void)n_in; (void)out_size; (void)ws_size;
  const float* inputs = (const float*)d_in[0];
  const float* noise  = (const float*)d_in[1];
  const float* mu     = (const float*)d_in[2];
  const float* ls     = (const float*)d_in[3];
  const float* Wq     = (const float*)d_in[4];
  const float* Wk     = (const float*)d_in[5];
  const float* Wv     = (const float*)d_in[6];
  const float* gwi    = (const float*)d_in[7];
  const float* gwh    = (const float*)d_in[8];
  const float* gbi    = (const float*)d_in[9];
  const float* gbh    = (const float*)d_in[10];
  const float* w1     = (const float*)d_in[11];
  const float* b1     = (const float*)d_in[12];
  const float* w2     = (const float*)d_in[13];
  const float* b2     = (const float*)d_in[14];
  const float* gin    = (const float*)d_in[15];
  const float* bin    = (const float*)d_in[16];
  const float* gs     = (const float*)d_in[17];
  const float* bs     = (const float*)d_in[18];
  const float* gff    = (const float*)d_in[19];
  const float* bff    = (const float*)d_in[20];

  // workspace layout
  f16*   k_h   = (f16*)d_ws;                                   // 64 MB
  f16*   v_h   = k_h + (size_t)B_ * N_ * D_;                   // 64 MB
  float* w     = (float*)(v_h + (size_t)B_ * N_ * D_);         // 8 MB
  float* stats = w + (size_t)B_ * N_ * NS_;                    // 2 MB
  float* slots = stats + (size_t)2 * B_ * N_;
  float* q     = slots + B_ * NS_ * D_;
  float* asum  = q + B_ * NS_ * D_;
  float* upd   = asum + 512;
  float* wiT   = upd + B_ * NS_ * D_;
  float* whT   = wiT + 768 * 256;
  f16*   WkT   = (f16*)(whT + 768 * 256);
  f16*   WvT   = WkT + 256 * 256;

  k_wcast<<<256, 256, 0, stream>>>(Wk, Wv, WkT, WvT);
  k_transpose<<<768, 256, 0, stream>>>(gwi, gwh, wiT, whT);
  k_init_slots<<<512, 256, 0, stream>>>(noise, mu, ls, slots);
  k_stats<<<B_ * N_ / 4, 256, 0, stream>>>(inputs, stats);
  k_kv_mfma<<<B_ * N_ / 128, 512, 0, stream>>>(inputs, stats, gin, bin, WkT, WvT, k_h, v_h);
  for (int it = 0; it < 4; ++it) {
    k_qproj<<<512, 256, 0, stream>>>(slots, gs, bs, Wq, q);
    hipMemsetAsync(asum, 0, (512 + B_ * NS_ * D_) * sizeof(float), stream);
    k_attn<<<dim3(16, 64), 128, 0, stream>>>(k_h, q, w, asum);
    k_updates<<<dim3(8, 64), 256, 0, stream>>>(v_h, w, upd);
    float* outp = (it == 3) ? (float*)d_out : slots;
    k_gru_mlp<<<512, 256, 0, stream>>>(upd, asum, slots, wiT, whT, gbi, gbh,
                                       w1, b1, w2, b2, gff, bff, outp);
  }
}

// Round 5
// 1166.631 us; speedup vs baseline: 1.8834x; 1.1506x over previous
//
#include <hip/hip_runtime.h>
#include <cstdint>

#define B_ 64
#define N_ 4096
#define D_ 256
#define NS_ 8
#define HID_ 512
#define EPS_ 1e-8f
#define SCALE_ 0.0625f
#define LN_EPS_ 1e-5f

typedef _Float16 f16;
typedef __attribute__((ext_vector_type(4))) _Float16 f16x4;
typedef __attribute__((ext_vector_type(8))) _Float16 f16x8;
typedef __attribute__((ext_vector_type(4))) float f32x4;

#define MFMA16(a, b, c) __builtin_amdgcn_mfma_f32_16x16x32_f16(a, b, c, 0, 0, 0)
// LDS swizzle: rows are 32 f16 (64 B); spread 4 consecutive rows across 16B slots.
// col must be a multiple of 8 (16 B unit); stays in [0,32).
#define SWZ(row, col) ((col) ^ (((row) & 3) << 3))

// ---------------- transpose GRU weights [768][256] -> [256][768] ----------------
__global__ void k_transpose(const float* __restrict__ wi, const float* __restrict__ wh,
                            float* __restrict__ wiT, float* __restrict__ whT) {
  int idx = blockIdx.x * 256 + threadIdx.x;      // 0..196607
  int o = idx >> 8;                              // 0..767
  int d = idx & 255;
  wiT[d * 768 + o] = wi[idx];
  whT[d * 768 + o] = wh[idx];
}

// ---------------- cast+transpose Wk/Wv [d][n] fp32 -> [n][d] fp16 ----------------
__global__ void k_wcast(const float* __restrict__ Wk, const float* __restrict__ Wv,
                        f16* __restrict__ WkT, f16* __restrict__ WvT) {
  int n = blockIdx.x, d = threadIdx.x;
  WkT[n * 256 + d] = (f16)Wk[d * 256 + n];
  WvT[n * 256 + d] = (f16)Wv[d * 256 + n];
}

// ---------------- slots init: mu + exp(logsigma)*noise ----------------
__global__ void k_init_slots(const float* __restrict__ noise, const float* __restrict__ mu,
                             const float* __restrict__ ls, float* __restrict__ slots) {
  int idx = blockIdx.x * 256 + threadIdx.x;      // 0..131071
  int d = idx & 255;
  slots[idx] = mu[d] + __expf(ls[d]) * noise[idx];
}

// ---------------- k = LN(x)@Wk, v = LN(x)@Wv  (fp16 MFMA, fp32 accum, LN fused) ----
// block: 256 thr (4 waves), tile 64 rows x 256 cols, BK=32
__global__ __launch_bounds__(256) void k_kv_mfma(
    const float* __restrict__ in,
    const float* __restrict__ g, const float* __restrict__ bb,
    const f16* __restrict__ WkT, const f16* __restrict__ WvT,
    f16* __restrict__ k, f16* __restrict__ v) {
  __shared__ __align__(16) char smem[36864];
  f16* As  = (f16*)smem;            // [64][32]  swizzled, 4 KB
  f16* Bks = (f16*)(smem + 4096);   // [256][32] swizzled, 16 KB
  f16* Bvs = (f16*)(smem + 20480);  // [256][32] swizzled, 16 KB
  const int tid = threadIdx.x;
  const int m0 = blockIdx.x * 64;
  const int arow = tid >> 2;            // 0..63
  const int q4 = tid & 3;
  const int acol = q4 * 8;

  // ---- fused LN stats: 4 lanes per row, 64 f32 each ----
  float s1 = 0.f, s2 = 0.f;
  {
    const float* rp = in + (size_t)(m0 + arow) * D_ + q4 * 64;
    #pragma unroll
    for (int i = 0; i < 16; ++i) {
      float4 a = *(const float4*)(rp + i * 4);
      s1 += a.x + a.y + a.z + a.w;
      s2 += a.x * a.x + a.y * a.y + a.z * a.z + a.w * a.w;
    }
    s1 += __shfl_xor(s1, 1, 64); s2 += __shfl_xor(s2, 1, 64);
    s1 += __shfl_xor(s1, 2, 64); s2 += __shfl_xor(s2, 2, 64);
  }
  const float mu = s1 * (1.f / D_);
  const float rs = rsqrtf(s2 * (1.f / D_) - mu * mu + LN_EPS_);

  // wave -> output subtile
  const int wid = tid >> 6;
  const int lane = tid & 63;
  const int wr = wid >> 1;            // 0..1: rows wr*32..+32
  const int wc = wid & 1;             // 0..1: cols wc*128..+128
  const int frow = lane & 15;
  const int kgrp = (lane >> 4) * 8;

  f32x4 acck[2][8], accv[2][8];
  #pragma unroll
  for (int f = 0; f < 2; ++f)
    #pragma unroll
    for (int c = 0; c < 8; ++c) {
      acck[f][c] = (f32x4){0.f, 0.f, 0.f, 0.f};
      accv[f][c] = (f32x4){0.f, 0.f, 0.f, 0.f};
    }

  #pragma unroll 1
  for (int kk = 0; kk < 8; ++kk) {
    const int d0 = kk * 32;
    __syncthreads();
    // stage A (LN applied, fp32 -> fp16), swizzled
    {
      const float* src = in + (size_t)(m0 + arow) * D_ + d0 + acol;
      float4 x0 = *(const float4*)(src);
      float4 x1 = *(const float4*)(src + 4);
      float4 g0 = *(const float4*)(g + d0 + acol);
      float4 g1 = *(const float4*)(g + d0 + acol + 4);
      float4 b0 = *(const float4*)(bb + d0 + acol);
      float4 b1 = *(const float4*)(bb + d0 + acol + 4);
      f16x8 av;
      av[0] = (f16)((x0.x - mu) * rs * g0.x + b0.x);
      av[1] = (f16)((x0.y - mu) * rs * g0.y + b0.y);
      av[2] = (f16)((x0.z - mu) * rs * g0.z + b0.z);
      av[3] = (f16)((x0.w - mu) * rs * g0.w + b0.w);
      av[4] = (f16)((x1.x - mu) * rs * g1.x + b1.x);
      av[5] = (f16)((x1.y - mu) * rs * g1.y + b1.y);
      av[6] = (f16)((x1.z - mu) * rs * g1.z + b1.z);
      av[7] = (f16)((x1.w - mu) * rs * g1.w + b1.w);
      *(f16x8*)&As[arow * 32 + SWZ(arow, acol)] = av;
    }
    // stage B: thread = one n-row, 32 d (4x f16x8), swizzled
    {
      const f16* sk = WkT + (size_t)tid * 256 + d0;
      const f16* sv = WvT + (size_t)tid * 256 + d0;
      #pragma unroll
      for (int c = 0; c < 4; ++c) {
        *(f16x8*)&Bks[tid * 32 + SWZ(tid, c * 8)] = *(const f16x8*)(sk + c * 8);
        *(f16x8*)&Bvs[tid * 32 + SWZ(tid, c * 8)] = *(const f16x8*)(sv + c * 8);
      }
    }
    __syncthreads();
    f16x8 af[2];
    #pragma unroll
    for (int f = 0; f < 2; ++f) {
      const int R = wr * 32 + f * 16 + frow;
      af[f] = *(const f16x8*)&As[R * 32 + SWZ(R, kgrp)];
    }
    #pragma unroll
    for (int cf = 0; cf < 8; ++cf) {
      const int n = wc * 128 + cf * 16 + frow;
      f16x8 bk = *(const f16x8*)&Bks[n * 32 + SWZ(n, kgrp)];
      f16x8 bv = *(const f16x8*)&Bvs[n * 32 + SWZ(n, kgrp)];
      acck[0][cf] = MFMA16(af[0], bk, acck[0][cf]);
      acck[1][cf] = MFMA16(af[1], bk, acck[1][cf]);
      accv[0][cf] = MFMA16(af[0], bv, accv[0][cf]);
      accv[1][cf] = MFMA16(af[1], bv, accv[1][cf]);
    }
  }
  // epilogue: D layout col=lane&15, row=(lane>>4)*4+r  (writes coalesce OK per PMC)
  const int drow = (lane >> 4) * 4;
  const int dcol = lane & 15;
  #pragma unroll
  for (int f = 0; f < 2; ++f)
    #pragma unroll
    for (int cf = 0; cf < 8; ++cf) {
      size_t base = (size_t)(m0 + wr * 32 + f * 16 + drow) * D_ + wc * 128 + cf * 16 + dcol;
      #pragma unroll
      for (int r = 0; r < 4; ++r) {
        k[base + (size_t)r * D_] = (f16)acck[f][cf][r];
        v[base + (size_t)r * D_] = (f16)accv[f][cf][r];
      }
    }
}

// ---------------- q = LN(slots)@Wq * SCALE  (block per row) ----------------
__global__ __launch_bounds__(256) void k_qproj(const float* __restrict__ slots,
    const float* __restrict__ g, const float* __restrict__ b,
    const float* __restrict__ Wq, float* __restrict__ q) {
  const int row = blockIdx.x;
  const int t = threadIdx.x;
  __shared__ float sl[256];
  __shared__ float red1[4], red2[4];
  float val = slots[(size_t)row * D_ + t];
  float s1 = val, s2 = val * val;
  #pragma unroll
  for (int m = 32; m >= 1; m >>= 1) { s1 += __shfl_xor(s1, m, 64); s2 += __shfl_xor(s2, m, 64); }
  int wave = t >> 6, lane = t & 63;
  if (lane == 0) { red1[wave] = s1; red2[wave] = s2; }
  __syncthreads();
  s1 = red1[0] + red1[1] + red1[2] + red1[3];
  s2 = red2[0] + red2[1] + red2[2] + red2[3];
  float mean = s1 * (1.f / D_);
  float var  = s2 * (1.f / D_) - mean * mean;
  float rstd = rsqrtf(var + LN_EPS_);
  sl[t] = (val - mean) * rstd * g[t] + b[t];
  __syncthreads();
  float a0 = 0.f, a1 = 0.f, a2 = 0.f, a3 = 0.f;
  #pragma unroll 8
  for (int d = 0; d < D_; d += 4) {
    a0 = fmaf(sl[d],     Wq[(d)     * D_ + t], a0);
    a1 = fmaf(sl[d + 1], Wq[(d + 1) * D_ + t], a1);
    a2 = fmaf(sl[d + 2], Wq[(d + 2) * D_ + t], a2);
    a3 = fmaf(sl[d + 3], Wq[(d + 3) * D_ + t], a3);
  }
  q[(size_t)row * D_ + t] = (a0 + a1 + a2 + a3) * SCALE_;
}

// ---------------- fused: dots + softmax(slots) + renorm-sum + updates ----------------
// block: 256 thr, 256 tokens; phase A thread-per-token, phase B wave-per-2-slots
__global__ __launch_bounds__(256) void k_attn_upd(
    const f16* __restrict__ k, const f16* __restrict__ v,
    const float* __restrict__ q, float* __restrict__ upd, float* __restrict__ asum) {
  const int b = blockIdx.y;
  const int jt = blockIdx.x * 256;
  const int tid = threadIdx.x;
  __shared__ float wv_s[256 * 9];   // [token][slot], pad 9 for conflict-free scalar access
  const float* qb = q + (size_t)b * NS_ * D_;   // uniform across threads -> scalar loads

  // ---- phase A: dots[8] for my token ----
  float dots[8] = {0.f, 0.f, 0.f, 0.f, 0.f, 0.f, 0.f, 0.f};
  {
    const f16* kr = k + ((size_t)b * N_ + jt + tid) * D_;
    #pragma unroll 2
    for (int c = 0; c < 8; ++c) {          // 8 superchunks of 32 d (64 B contiguous)
      f16x8 kk[4];
      #pragma unroll
      for (int j = 0; j < 4; ++j) kk[j] = *(const f16x8*)(kr + c * 32 + j * 8);
      #pragma unroll
      for (int j = 0; j < 4; ++j) {
        float kf[8];
        #pragma unroll
        for (int e = 0; e < 8; ++e) kf[e] = (float)kk[j][e];
        #pragma unroll
        for (int i = 0; i < 8; ++i) {
          const float* qq = qb + i * D_ + c * 32 + j * 8;
          float acc = dots[i];
          #pragma unroll
          for (int e = 0; e < 8; ++e) acc = fmaf(kf[e], qq[e], acc);
          dots[i] = acc;
        }
      }
    }
  }
  // softmax over slots + EPS
  {
    float m = dots[0];
    #pragma unroll
    for (int i = 1; i < 8; ++i) m = fmaxf(m, dots[i]);
    float e[8], s = 0.f;
    #pragma unroll
    for (int i = 0; i < 8; ++i) { e[i] = __expf(dots[i] - m); s += e[i]; }
    float is = 1.f / s;
    #pragma unroll
    for (int i = 0; i < 8; ++i) {
      float wv = e[i] * is + EPS_;
      wv_s[tid * 9 + i] = wv;
      // wave-reduce this slot's sum over tokens -> one atomic per wave
      float vv = wv;
      #pragma unroll
      for (int mm = 32; mm >= 1; mm >>= 1) vv += __shfl_xor(vv, mm, 64);
      if ((tid & 63) == 0) atomicAdd(&asum[b * NS_ + i], vv);
    }
  }
  __syncthreads();

  // ---- phase B: upd[i0..i0+1][lane*4..+4] += sum_j wv[j][i] * v[j][d] ----
  {
    const int wave = tid >> 6, lane = tid & 63;
    const int i0 = wave * 2;
    const f16* vb = v + ((size_t)b * N_ + jt) * D_;
    float a0[4] = {0.f, 0.f, 0.f, 0.f};
    float a1[4] = {0.f, 0.f, 0.f, 0.f};
    #pragma unroll 4
    for (int jj = 0; jj < 256; ++jj) {
      f16x4 vvh = *(const f16x4*)(vb + (size_t)jj * D_ + lane * 4);
      float vx = (float)vvh[0], vy = (float)vvh[1], vz = (float)vvh[2], vw = (float)vvh[3];
      float wa = wv_s[jj * 9 + i0];
      float wc = wv_s[jj * 9 + i0 + 1];
      a0[0] = fmaf(wa, vx, a0[0]); a0[1] = fmaf(wa, vy, a0[1]);
      a0[2] = fmaf(wa, vz, a0[2]); a0[3] = fmaf(wa, vw, a0[3]);
      a1[0] = fmaf(wc, vx, a1[0]); a1[1] = fmaf(wc, vy, a1[1]);
      a1[2] = fmaf(wc, vz, a1[2]); a1[3] = fmaf(wc, vw, a1[3]);
    }
    float* u0 = upd + ((size_t)b * NS_ + i0) * D_ + lane * 4;
    float* u1 = u0 + D_;
    #pragma unroll
    for (int c = 0; c < 4; ++c) { atomicAdd(u0 + c, a0[c]); atomicAdd(u1 + c, a1[c]); }
  }
}

// ---------------- GRU + LN + MLP residual (block per slot-row) ----------------
__global__ __launch_bounds__(256) void k_gru_mlp(
    const float* __restrict__ upd, const float* __restrict__ asum,
    const float* __restrict__ slots,
    const float* __restrict__ wiT, const float* __restrict__ whT,
    const float* __restrict__ bi, const float* __restrict__ bh,
    const float* __restrict__ w1, const float* __restrict__ b1,
    const float* __restrict__ w2, const float* __restrict__ b2,
    const float* __restrict__ gf, const float* __restrict__ bf,
    float* __restrict__ out) {
  const int row = blockIdx.x;   // 0..511 = b*8+i
  const int t = threadIdx.x;
  __shared__ float xs[256], hs[256], ffs[256], hid[512];
  __shared__ float red1[4], red2[4];
  const float ia = 1.f / asum[row];
  const float xv = upd[(size_t)row * D_ + t] * ia;
  const float hv = slots[(size_t)row * D_ + t];
  xs[t] = xv; hs[t] = hv;
  __syncthreads();
  float gi0 = bi[t], gi1 = bi[D_ + t], gi2 = bi[2 * D_ + t];
  float gh0 = bh[t], gh1 = bh[D_ + t], gh2 = bh[2 * D_ + t];
  #pragma unroll 8
  for (int d = 0; d < D_; ++d) {
    float xd = xs[d], hd = hs[d];
    const float* wid = wiT + d * 768;
    const float* whd = whT + d * 768;
    gi0 = fmaf(xd, wid[t], gi0); gi1 = fmaf(xd, wid[D_ + t], gi1); gi2 = fmaf(xd, wid[2 * D_ + t], gi2);
    gh0 = fmaf(hd, whd[t], gh0); gh1 = fmaf(hd, whd[D_ + t], gh1); gh2 = fmaf(hd, whd[2 * D_ + t], gh2);
  }
  float r = 1.f / (1.f + __expf(-(gi0 + gh0)));
  float z = 1.f / (1.f + __expf(-(gi1 + gh1)));
  float n = tanhf(gi2 + r * gh2);
  float hnew = (1.f - z) * n + z * hv;
  // LayerNorm(hnew) across block
  float s1 = hnew, s2 = hnew * hnew;
  #pragma unroll
  for (int m = 32; m >= 1; m >>= 1) { s1 += __shfl_xor(s1, m, 64); s2 += __shfl_xor(s2, m, 64); }
  const int wave = t >> 6, lane = t & 63;
  if (lane == 0) { red1[wave] = s1; red2[wave] = s2; }
  __syncthreads();
  s1 = red1[0] + red1[1] + red1[2] + red1[3];
  s2 = red2[0] + red2[1] + red2[2] + red2[3];
  float mean = s1 * (1.f / D_);
  float var  = s2 * (1.f / D_) - mean * mean;
  float rstd = rsqrtf(var + LN_EPS_);
  ffs[t] = (hnew - mean) * rstd * gf[t] + bf[t];
  __syncthreads();
  float h1a = b1[t], h2a = b1[D_ + t], h1b = 0.f, h2b = 0.f;
  #pragma unroll 8
  for (int d = 0; d < D_; d += 2) {
    float f0 = ffs[d], f1 = ffs[d + 1];
    h1a = fmaf(f0, w1[(size_t)(d)     * HID_ + t],       h1a);
    h2a = fmaf(f0, w1[(size_t)(d)     * HID_ + D_ + t],  h2a);
    h1b = fmaf(f1, w1[(size_t)(d + 1) * HID_ + t],       h1b);
    h2b = fmaf(f1, w1[(size_t)(d + 1) * HID_ + D_ + t],  h2b);
  }
  hid[t] = fmaxf(h1a + h1b, 0.f); hid[D_ + t] = fmaxf(h2a + h2b, 0.f);
  __syncthreads();
  float oa = b2[t], ob = 0.f;
  #pragma unroll 8
  for (int d = 0; d < HID_; d += 2) {
    oa = fmaf(hid[d],     w2[(size_t)(d)     * D_ + t], oa);
    ob = fmaf(hid[d + 1], w2[(size_t)(d + 1) * D_ + t], ob);
  }
  out[(size_t)row * D_ + t] = oa + ob + hnew;
}

extern "C" void kernel_launch(void* const* d_in, const int* in_sizes, int n_in,
                              void* d_out, int out_size, void* d_ws, size_t ws_size,
                              hipStream_t stream) {
  (void)in_sizes; (void)n_in; (void)out_size; (void)ws_size;
  const float* inputs = (const float*)d_in[0];
  const float* noise  = (const float*)d_in[1];
  const float* mu     = (const float*)d_in[2];
  const float* ls     = (const float*)d_in[3];
  const float* Wq     = (const float*)d_in[4];
  const float* Wk     = (const float*)d_in[5];
  const float* Wv     = (const float*)d_in[6];
  const float* gwi    = (const float*)d_in[7];
  const float* gwh    = (const float*)d_in[8];
  const float* gbi    = (const float*)d_in[9];
  const float* gbh    = (const float*)d_in[10];
  const float* w1     = (const float*)d_in[11];
  const float* b1     = (const float*)d_in[12];
  const float* w2     = (const float*)d_in[13];
  const float* b2     = (const float*)d_in[14];
  const float* gin    = (const float*)d_in[15];
  const float* bin    = (const float*)d_in[16];
  const float* gs     = (const float*)d_in[17];
  const float* bs     = (const float*)d_in[18];
  const float* gff    = (const float*)d_in[19];
  const float* bff    = (const float*)d_in[20];

  // workspace layout
  const size_t KV = (size_t)B_ * N_ * D_;        // 67.1M elems
  f16*   k_h   = (f16*)d_ws;                     // 134 MB
  f16*   v_h   = k_h + KV;                       // 134 MB
  float* slots = (float*)(v_h + KV);
  float* q     = slots + (size_t)B_ * NS_ * D_;
  float* asum  = q + (size_t)B_ * NS_ * D_;
  float* upd   = asum + 512;
  float* wiT   = upd + (size_t)B_ * NS_ * D_;
  float* whT   = wiT + 768 * 256;
  f16*   WkT   = (f16*)(whT + 768 * 256);
  f16*   WvT   = WkT + 256 * 256;

  k_wcast<<<256, 256, 0, stream>>>(Wk, Wv, WkT, WvT);
  k_transpose<<<768, 256, 0, stream>>>(gwi, gwh, wiT, whT);
  k_init_slots<<<512, 256, 0, stream>>>(noise, mu, ls, slots);
  k_kv_mfma<<<B_ * N_ / 64, 256, 0, stream>>>(inputs, gin, bin, WkT, WvT, k_h, v_h);
  for (int it = 0; it < 4; ++it) {
    k_qproj<<<512, 256, 0, stream>>>(slots, gs, bs, Wq, q);
    hipMemsetAsync(asum, 0, (512 + B_ * NS_ * D_) * sizeof(float), stream);
    k_attn_upd<<<dim3(16, 64), 256, 0, stream>>>(k_h, v_h, q, upd, asum);
    float* outp = (it == 3) ? (float*)d_out : slots;
    k_gru_mlp<<<512, 256, 0, stream>>>(upd, asum, slots, wiT, whT, gbi, gbh,
                                       w1, b1, w2, b2, gff, bff, outp);
  }
}